// Round 3
// baseline (596.744 us; speedup 1.0000x reference)
//
#include <hip/hip_runtime.h>

// WaveNet on MI355X — round 3: transaction-oriented rewrite.
//  - sacc eliminated: z stored bf16 per layer; skip GEMM (K=576) moved to final_kernel
//  - all global I/O 16B/lane coalesced via wave-private LDS transpose (zt reuse)
//  - layer: 512-thr blocks, wave=32t, acc[2][8]=64 VGPR, launch_bounds(512,4) -> 2 blk/CU
// ws: hA 16 + hB 16 + z 144 + weights 0.62 = ~177 MB

#define T_LEN 32768
#define N_B 4

typedef unsigned short u16;
typedef __attribute__((ext_vector_type(8))) short short8;
typedef __attribute__((ext_vector_type(4))) float f32x4;

#define MFMA16(a, b, c) __builtin_amdgcn_mfma_f32_16x16x32_bf16((a), (b), (c), 0, 0, 0)

__device__ __forceinline__ u16 bf16_rne(float f) {
    unsigned u = __float_as_uint(f);
    u += 0x7FFFu + ((u >> 16) & 1u);
    return (u16)(u >> 16);
}
__device__ __forceinline__ float bf16_to_f(u16 h) {
    return __uint_as_float(((unsigned)h) << 16);
}
__device__ __forceinline__ float fast_tanh(float x) {
    float e = __expf(2.f * x);
    return 1.f - 2.f * __builtin_amdgcn_rcpf(e + 1.f);
}
__device__ __forceinline__ float fast_sigmoid(float x) {
    return __builtin_amdgcn_rcpf(1.f + __expf(-x));
}

// ---- weight prepack: fp32 -> bf16, conv weights reordered to [l][o][k=tap*64+c] ----
__global__ __launch_bounds__(256) void pack_kernel(
    const float* __restrict__ wc, const float* __restrict__ wo,
    const float* __restrict__ w1, const float* __restrict__ w2,
    u16* __restrict__ Wc, u16* __restrict__ Wo, u16* __restrict__ W1p, u16* __restrict__ W2p)
{
    int i = blockIdx.x * 256 + threadIdx.x;
    if (i < 221184) {                       // 9*128*192 conv
        int l = i / 24576, rem = i % 24576;
        int o = rem / 192, k = rem % 192;
        int tap = k / 64, c = k % 64;
        Wc[i] = bf16_rne(wc[((l * 128 + o) * 64 + c) * 3 + tap]);
    } else if (i < 258048) {                // 9*64*64 residual 1x1
        int j = i - 221184; Wo[j] = bf16_rne(wo[j]);
    } else if (i < 294912) {                // 64*576 out1 (row-major [o][k])
        int j = i - 258048; W1p[j] = bf16_rne(w1[j]);
    } else if (i < 311296) {                // 256*64 out2 (row-major [o][k])
        int j = i - 294912; W2p[j] = bf16_rne(w2[j]);
    }
}

// ---- input 1x1 conv + tanh: x(B,1,T) -> h(B,T,64) bf16 ----
__global__ __launch_bounds__(256) void input_kernel(
    const float* __restrict__ x, const float* __restrict__ wi,
    const float* __restrict__ bi, u16* __restrict__ h)
{
    const int id = blockIdx.x * 256 + threadIdx.x;   // = b*T + t
    const float xv = x[id];
    u16* dst = h + (size_t)id * 64;
    #pragma unroll
    for (int c8 = 0; c8 < 8; ++c8) {
        unsigned w[4];
        #pragma unroll
        for (int p2 = 0; p2 < 4; ++p2) {
            int c = c8 * 8 + p2 * 2;
            unsigned lo = bf16_rne(fast_tanh(xv * wi[c]     + bi[c]));
            unsigned hi = bf16_rne(fast_tanh(xv * wi[c + 1] + bi[c + 1]));
            w[p2] = lo | (hi << 16);
        }
        uint4 v = make_uint4(w[0], w[1], w[2], w[3]);
        *(uint4*)(dst + c8 * 8) = v;
    }
}

// ---- per-layer: dilated conv -> gate -> z store + residual h-update (all coalesced) ----
// grid (T/256, B), 512 threads (8 waves); wave owns 32 t (2 x 16-t chunks) x 128 o.
__global__ __launch_bounds__(512, 4) void layer_kernel(
    const u16* __restrict__ hIn, u16* __restrict__ hOut, u16* __restrict__ zbuf,
    const u16* __restrict__ Wconv, const u16* __restrict__ Wout,
    const float* __restrict__ bconv, const float* __restrict__ bout,
    int layer, int dil)
{
    __shared__ u16 wshC[6 * 128 * 4 * 8];   // 48 KB  conv frags [ks][o][quad][8]
    __shared__ u16 wshO[2 * 64 * 4 * 8];    // 8 KB   res  frags
    __shared__ u16 zt[8][16][72];           // 18 KB  per-wave transpose tile (z, then res)

    const int b = blockIdx.y;
    const int tid = threadIdx.x;
    const int wv = tid >> 6, lane = tid & 63;
    const int quad = lane >> 4, col = lane & 15;

    const u16* wl  = Wconv + layer * (128 * 192);
    const u16* wol = Wout  + layer * (64 * 64);

    #pragma unroll
    for (int rep = 0; rep < 6; ++rep) {                // 3072 x 16B conv frags
        int i = rep * 512 + tid;
        int o = i / 24, m = i % 24, ks = m >> 2, q = m & 3;
        *(short8*)&wshC[((ks * 128 + o) * 4 + q) * 8] =
            *(const short8*)(wl + o * 192 + ks * 32 + q * 8);
    }
    {                                                  // 512 x 16B res frags
        int r = tid >> 3, m = tid & 7, ks = m >> 2, q = m & 3;
        *(short8*)&wshO[((ks * 64 + r) * 4 + q) * 8] =
            *(const short8*)(wol + r * 64 + ks * 32 + q * 8);
    }
    __syncthreads();   // only block barrier

    const float* bcl = bconv + layer * 128;
    float ba[4], bg[4], bo_[4];
    #pragma unroll
    for (int j = 0; j < 4; ++j) {
        ba[j]  = bcl[j * 16 + col];
        bg[j]  = bcl[64 + j * 16 + col];
        bo_[j] = bout[layer * 64 + j * 16 + col];
    }

    const int t0 = blockIdx.x * 256 + wv * 32;
    const f32x4 Z = {0.f, 0.f, 0.f, 0.f};

    // --- dilated conv GEMM: 32 t x 128 o, K = 192 ---
    f32x4 acc[2][8];
    #pragma unroll
    for (int n2 = 0; n2 < 2; ++n2)
        #pragma unroll
        for (int j = 0; j < 8; ++j) acc[n2][j] = Z;

    #pragma unroll
    for (int ks = 0; ks < 6; ++ks) {
        const int tap  = ks >> 1;
        const int back = (2 - tap) * dil;              // causal: w[tap] hits t-(2-tap)*d
        const int cb   = (ks & 1) * 32 + quad * 8;
        short8 af[2];
        #pragma unroll
        for (int n2 = 0; n2 < 2; ++n2) {
            const int tt = t0 + n2 * 16 + col - back;
            af[n2] = short8{};
            if (tt >= 0)
                af[n2] = *(const short8*)(hIn + ((size_t)(b * T_LEN + tt) * 64 + cb));
        }
        #pragma unroll
        for (int j = 0; j < 8; ++j) {
            short8 wf = *(const short8*)&wshC[((ks * 128 + j * 16 + col) * 4 + quad) * 8];
            #pragma unroll
            for (int n2 = 0; n2 < 2; ++n2)
                acc[n2][j] = MFMA16(af[n2], wf, acc[n2][j]);
        }
    }

    // --- per 16-t chunk: gate -> z (via zt) -> res GEMM -> h update (via zt reuse) ---
    u16* zl = zbuf + (size_t)layer * N_B * T_LEN * 64;
    #pragma unroll
    for (int n2 = 0; n2 < 2; ++n2) {
        const int tc = t0 + n2 * 16;

        #pragma unroll
        for (int j = 0; j < 4; ++j)
            #pragma unroll
            for (int r = 0; r < 4; ++r) {
                float a = acc[n2][j][r] + ba[j];
                float g = acc[n2][4 + j][r] + bg[j];
                zt[wv][quad * 4 + r][j * 16 + col] =
                    bf16_rne(fast_tanh(a) * fast_sigmoid(g));
            }

        // coalesced z store: lane covers 32 contiguous bytes of the 16t x 64ch chunk
        const int zr = lane >> 2, zc = (lane & 3) * 16;
        {
            u16* zdst = zl + ((size_t)(b * T_LEN + tc + zr) * 64 + zc);
            *(short8*)zdst       = *(const short8*)&zt[wv][zr][zc];
            *(short8*)(zdst + 8) = *(const short8*)&zt[wv][zr][zc + 8];
        }

        // residual GEMM: K = 64
        f32x4 hacc[4];
        #pragma unroll
        for (int j = 0; j < 4; ++j) hacc[j] = Z;
        #pragma unroll
        for (int ks = 0; ks < 2; ++ks) {
            short8 afz = *(const short8*)&zt[wv][col][ks * 32 + quad * 8];
            #pragma unroll
            for (int j = 0; j < 4; ++j) {
                short8 wf = *(const short8*)&wshO[((ks * 64 + j * 16 + col) * 4 + quad) * 8];
                hacc[j] = MFMA16(afz, wf, hacc[j]);
            }
        }

        // res+bias -> zt (reuse; per-wave in-order LDS keeps this safe)
        #pragma unroll
        for (int j = 0; j < 4; ++j)
            #pragma unroll
            for (int r = 0; r < 4; ++r)
                zt[wv][quad * 4 + r][j * 16 + col] = bf16_rne(hacc[j][r] + bo_[j]);

        // coalesced h update: h_next = hIn + res
        const size_t hb = (size_t)(b * T_LEN + tc + zr) * 64 + zc;
        #pragma unroll
        for (int s = 0; s < 2; ++s) {
            short8 hv = *(const short8*)(hIn + hb + s * 8);
            short8 rv = *(const short8*)&zt[wv][zr][zc + s * 8];
            short8 ov;
            #pragma unroll
            for (int e = 0; e < 8; ++e)
                ov[e] = (short)bf16_rne(bf16_to_f((u16)hv[e]) + bf16_to_f((u16)rv[e]));
            *(short8*)(hOut + hb + s * 8) = ov;
        }
    }
}

// ---- final: u = tanh(W1 @ concat(z) + b1); out = W2 @ u + b2 ----
// grid (T/512, B), 512 threads (8 waves); wave owns 64 t (4 x 16-t chunks).
__global__ __launch_bounds__(512, 2) void final_kernel(
    const u16* __restrict__ zbuf, const u16* __restrict__ W1, const u16* __restrict__ W2,
    const float* __restrict__ b1, const float* __restrict__ b2, float* __restrict__ out)
{
    __shared__ u16 w1sh[18 * 64 * 4 * 8];   // 72 KB [ks][o][quad][8], K = 576
    __shared__ u16 w2sh[2 * 256 * 4 * 8];   // 32 KB
    __shared__ u16 ut[8][16][72];           // 18 KB per-wave u transpose

    const int b = blockIdx.y;
    const int tid = threadIdx.x;
    const int wv = tid >> 6, lane = tid & 63;
    const int quad = lane >> 4, col = lane & 15;

    #pragma unroll
    for (int rep = 0; rep < 9; ++rep) {                 // 4608 x 16B
        int i = rep * 512 + tid;
        int o = i / 72, m = i % 72, ks = m >> 2, q = m & 3;
        *(short8*)&w1sh[((ks * 64 + o) * 4 + q) * 8] =
            *(const short8*)(W1 + o * 576 + ks * 32 + q * 8);
    }
    #pragma unroll
    for (int rep = 0; rep < 4; ++rep) {                 // 2048 x 16B
        int i = rep * 512 + tid;
        int o = (i >> 2) & 255, ks = i >> 10, q = i & 3;
        *(short8*)&w2sh[((ks * 256 + o) * 4 + q) * 8] =
            *(const short8*)(W2 + o * 64 + ks * 32 + q * 8);
    }
    __syncthreads();

    float b1v[4], b2v[16];
    #pragma unroll
    for (int j = 0; j < 4; ++j) b1v[j] = b1[j * 16 + col];
    #pragma unroll
    for (int nt = 0; nt < 16; ++nt) b2v[nt] = b2[nt * 16 + col];

    const int t0 = blockIdx.x * 512 + wv * 64;
    const f32x4 Z = {0.f, 0.f, 0.f, 0.f};

    for (int cc = 0; cc < 4; ++cc) {
        const int tc = t0 + cc * 16;
        const int t  = tc + col;

        // GEMM1: u(64) = W1 @ concat_l z_l, K = 576
        f32x4 acc1[4];
        #pragma unroll
        for (int j = 0; j < 4; ++j) acc1[j] = Z;
        #pragma unroll
        for (int ks = 0; ks < 18; ++ks) {
            const int l = ks >> 1;
            short8 zf = *(const short8*)(zbuf + (size_t)l * N_B * T_LEN * 64 +
                                         ((size_t)(b * T_LEN + t) * 64 + (ks & 1) * 32 + quad * 8));
            #pragma unroll
            for (int j = 0; j < 4; ++j) {
                short8 wf = *(const short8*)&w1sh[((ks * 64 + j * 16 + col) * 4 + quad) * 8];
                acc1[j] = MFMA16(zf, wf, acc1[j]);
            }
        }

        // u = tanh(. + b1) -> ut (D layout row=t, col=ch)
        #pragma unroll
        for (int j = 0; j < 4; ++j)
            #pragma unroll
            for (int r = 0; r < 4; ++r)
                ut[wv][quad * 4 + r][j * 16 + col] =
                    bf16_rne(fast_tanh(acc1[j][r] + b1v[j]));

        // GEMM2: out(256) = W2 @ u, K = 64; D[t][o] -> t-contiguous f32x4 stores
        short8 uf0 = *(const short8*)&ut[wv][col][quad * 8];
        short8 uf1 = *(const short8*)&ut[wv][col][32 + quad * 8];
        #pragma unroll
        for (int nt = 0; nt < 16; ++nt) {
            f32x4 a2 = Z;
            short8 w20 = *(const short8*)&w2sh[((nt * 16 + col) * 4 + quad) * 8];
            short8 w21 = *(const short8*)&w2sh[((256 + nt * 16 + col) * 4 + quad) * 8];
            a2 = MFMA16(uf0, w20, a2);
            a2 = MFMA16(uf1, w21, a2);
            float bb = b2v[nt];
            f32x4 res = {a2[0] + bb, a2[1] + bb, a2[2] + bb, a2[3] + bb};
            float* op = out + (size_t)(b * 256 + nt * 16 + col) * T_LEN + tc + quad * 4;
            *(f32x4*)op = res;
        }
    }
}

extern "C" void kernel_launch(void* const* d_in, const int* in_sizes, int n_in,
                              void* d_out, int out_size, void* d_ws, size_t ws_size,
                              hipStream_t stream)
{
    const float* x  = (const float*)d_in[0];
    const float* wi = (const float*)d_in[1];
    const float* bi = (const float*)d_in[2];
    const float* wc = (const float*)d_in[3];
    const float* bc = (const float*)d_in[4];
    const float* wo = (const float*)d_in[5];
    const float* bo = (const float*)d_in[6];
    const float* w1 = (const float*)d_in[7];
    const float* b1 = (const float*)d_in[8];
    const float* w2 = (const float*)d_in[9];
    const float* b2 = (const float*)d_in[10];
    float* out = (float*)d_out;

    char* ws = (char*)d_ws;
    const size_t HBYTES = (size_t)N_B * T_LEN * 64 * 2;   // 16 MB
    u16* hA   = (u16*)ws;
    u16* hB   = (u16*)(ws + HBYTES);
    u16* zAll = (u16*)(ws + 2 * HBYTES);                  // 9 x 16 MB
    size_t off = 2 * HBYTES + 9 * HBYTES;
    u16* Wc  = (u16*)(ws + off); off += (size_t)9 * 128 * 192 * 2;
    u16* Wo  = (u16*)(ws + off); off += (size_t)9 * 64 * 64 * 2;
    u16* W1p = (u16*)(ws + off); off += (size_t)64 * 576 * 2;
    u16* W2p = (u16*)(ws + off); off += (size_t)256 * 64 * 2;
    if (ws_size < off) return;   // needs ~177 MB of workspace

    pack_kernel<<<1216, 256, 0, stream>>>(wc, wo, w1, w2, Wc, Wo, W1p, W2p);
    input_kernel<<<(N_B * T_LEN) / 256, 256, 0, stream>>>(x, wi, bi, hA);

    static const int dil[9] = {1, 2, 4, 8, 16, 32, 64, 128, 256};
    for (int l = 0; l < 9; ++l) {
        const u16* hin = (l & 1) ? hB : hA;
        u16* hout      = (l & 1) ? hA : hB;
        layer_kernel<<<dim3(T_LEN / 256, N_B), 512, 0, stream>>>(
            hin, hout, zAll, Wc, Wo, bc, bo, l, dil[l]);
    }
    final_kernel<<<dim3(T_LEN / 512, N_B), 512, 0, stream>>>(zAll, W1p, W2p, b1, b2, out);
}

// Round 5
// 360.532 us; speedup vs baseline: 1.6552x; 1.6552x over previous
//
#include <hip/hip_runtime.h>

// WaveNet on MI355X — round 4 (resubmit; round-4 bench hit GPU-acquisition timeout).
//  - skip_kernel: K=576 GEMM -> u bf16 (16 MB); LDS exactly 80 KB -> 2 blocks/CU
//  - out_kernel: K=64 GEMM; stores routed through [o][t] LDS tile -> full-128B-line
//    coalesced 1-KB wave stores (kills the 232 MB partial-write-allocate over-fetch)
// ws: hA 16 + hB 16 + z 144 + u 16 + weights 0.62 = ~193 MB

#define T_LEN 32768
#define N_B 4

typedef unsigned short u16;
typedef __attribute__((ext_vector_type(8))) short short8;
typedef __attribute__((ext_vector_type(4))) float f32x4;

#define MFMA16(a, b, c) __builtin_amdgcn_mfma_f32_16x16x32_bf16((a), (b), (c), 0, 0, 0)

__device__ __forceinline__ u16 bf16_rne(float f) {
    unsigned u = __float_as_uint(f);
    u += 0x7FFFu + ((u >> 16) & 1u);
    return (u16)(u >> 16);
}
__device__ __forceinline__ float bf16_to_f(u16 h) {
    return __uint_as_float(((unsigned)h) << 16);
}
__device__ __forceinline__ float fast_tanh(float x) {
    float e = __expf(2.f * x);
    return 1.f - 2.f * __builtin_amdgcn_rcpf(e + 1.f);
}
__device__ __forceinline__ float fast_sigmoid(float x) {
    return __builtin_amdgcn_rcpf(1.f + __expf(-x));
}

// ---- weight prepack: fp32 -> bf16, conv weights reordered to [l][o][k=tap*64+c] ----
__global__ __launch_bounds__(256) void pack_kernel(
    const float* __restrict__ wc, const float* __restrict__ wo,
    const float* __restrict__ w1, const float* __restrict__ w2,
    u16* __restrict__ Wc, u16* __restrict__ Wo, u16* __restrict__ W1p, u16* __restrict__ W2p)
{
    int i = blockIdx.x * 256 + threadIdx.x;
    if (i < 221184) {                       // 9*128*192 conv
        int l = i / 24576, rem = i % 24576;
        int o = rem / 192, k = rem % 192;
        int tap = k / 64, c = k % 64;
        Wc[i] = bf16_rne(wc[((l * 128 + o) * 64 + c) * 3 + tap]);
    } else if (i < 258048) {                // 9*64*64 residual 1x1
        int j = i - 221184; Wo[j] = bf16_rne(wo[j]);
    } else if (i < 294912) {                // 64*576 out1 (row-major [o][k])
        int j = i - 258048; W1p[j] = bf16_rne(w1[j]);
    } else if (i < 311296) {                // 256*64 out2 (row-major [o][k])
        int j = i - 294912; W2p[j] = bf16_rne(w2[j]);
    }
}

// ---- input 1x1 conv + tanh: x(B,1,T) -> h(B,T,64) bf16 ----
__global__ __launch_bounds__(256) void input_kernel(
    const float* __restrict__ x, const float* __restrict__ wi,
    const float* __restrict__ bi, u16* __restrict__ h)
{
    const int id = blockIdx.x * 256 + threadIdx.x;   // = b*T + t
    const float xv = x[id];
    u16* dst = h + (size_t)id * 64;
    #pragma unroll
    for (int c8 = 0; c8 < 8; ++c8) {
        unsigned w[4];
        #pragma unroll
        for (int p2 = 0; p2 < 4; ++p2) {
            int c = c8 * 8 + p2 * 2;
            unsigned lo = bf16_rne(fast_tanh(xv * wi[c]     + bi[c]));
            unsigned hi = bf16_rne(fast_tanh(xv * wi[c + 1] + bi[c + 1]));
            w[p2] = lo | (hi << 16);
        }
        uint4 v = make_uint4(w[0], w[1], w[2], w[3]);
        *(uint4*)(dst + c8 * 8) = v;
    }
}

// ---- per-layer: dilated conv -> gate -> z store + residual h-update (all coalesced) ----
// grid (T/256, B), 512 threads (8 waves); wave owns 32 t (2 x 16-t chunks) x 128 o.
__global__ __launch_bounds__(512, 4) void layer_kernel(
    const u16* __restrict__ hIn, u16* __restrict__ hOut, u16* __restrict__ zbuf,
    const u16* __restrict__ Wconv, const u16* __restrict__ Wout,
    const float* __restrict__ bconv, const float* __restrict__ bout,
    int layer, int dil)
{
    __shared__ u16 wshC[6 * 128 * 4 * 8];   // 48 KB  conv frags [ks][o][quad][8]
    __shared__ u16 wshO[2 * 64 * 4 * 8];    // 8 KB   res  frags
    __shared__ u16 zt[8][16][72];           // 18 KB  per-wave transpose tile (z, then res)

    const int b = blockIdx.y;
    const int tid = threadIdx.x;
    const int wv = tid >> 6, lane = tid & 63;
    const int quad = lane >> 4, col = lane & 15;

    const u16* wl  = Wconv + layer * (128 * 192);
    const u16* wol = Wout  + layer * (64 * 64);

    #pragma unroll
    for (int rep = 0; rep < 6; ++rep) {                // 3072 x 16B conv frags
        int i = rep * 512 + tid;
        int o = i / 24, m = i % 24, ks = m >> 2, q = m & 3;
        *(short8*)&wshC[((ks * 128 + o) * 4 + q) * 8] =
            *(const short8*)(wl + o * 192 + ks * 32 + q * 8);
    }
    {                                                  // 512 x 16B res frags
        int r = tid >> 3, m = tid & 7, ks = m >> 2, q = m & 3;
        *(short8*)&wshO[((ks * 64 + r) * 4 + q) * 8] =
            *(const short8*)(wol + r * 64 + ks * 32 + q * 8);
    }
    __syncthreads();   // only block barrier

    const float* bcl = bconv + layer * 128;
    float ba[4], bg[4], bo_[4];
    #pragma unroll
    for (int j = 0; j < 4; ++j) {
        ba[j]  = bcl[j * 16 + col];
        bg[j]  = bcl[64 + j * 16 + col];
        bo_[j] = bout[layer * 64 + j * 16 + col];
    }

    const int t0 = blockIdx.x * 256 + wv * 32;
    const f32x4 Z = {0.f, 0.f, 0.f, 0.f};

    // --- dilated conv GEMM: 32 t x 128 o, K = 192 ---
    f32x4 acc[2][8];
    #pragma unroll
    for (int n2 = 0; n2 < 2; ++n2)
        #pragma unroll
        for (int j = 0; j < 8; ++j) acc[n2][j] = Z;

    #pragma unroll
    for (int ks = 0; ks < 6; ++ks) {
        const int tap  = ks >> 1;
        const int back = (2 - tap) * dil;              // causal: w[tap] hits t-(2-tap)*d
        const int cb   = (ks & 1) * 32 + quad * 8;
        short8 af[2];
        #pragma unroll
        for (int n2 = 0; n2 < 2; ++n2) {
            const int tt = t0 + n2 * 16 + col - back;
            af[n2] = short8{};
            if (tt >= 0)
                af[n2] = *(const short8*)(hIn + ((size_t)(b * T_LEN + tt) * 64 + cb));
        }
        #pragma unroll
        for (int j = 0; j < 8; ++j) {
            short8 wf = *(const short8*)&wshC[((ks * 128 + j * 16 + col) * 4 + quad) * 8];
            #pragma unroll
            for (int n2 = 0; n2 < 2; ++n2)
                acc[n2][j] = MFMA16(af[n2], wf, acc[n2][j]);
        }
    }

    // --- per 16-t chunk: gate -> z (via zt) -> res GEMM -> h update (via zt reuse) ---
    u16* zl = zbuf + (size_t)layer * N_B * T_LEN * 64;
    #pragma unroll
    for (int n2 = 0; n2 < 2; ++n2) {
        const int tc = t0 + n2 * 16;

        #pragma unroll
        for (int j = 0; j < 4; ++j)
            #pragma unroll
            for (int r = 0; r < 4; ++r) {
                float a = acc[n2][j][r] + ba[j];
                float g = acc[n2][4 + j][r] + bg[j];
                zt[wv][quad * 4 + r][j * 16 + col] =
                    bf16_rne(fast_tanh(a) * fast_sigmoid(g));
            }

        // coalesced z store: lane covers 32 contiguous bytes of the 16t x 64ch chunk
        const int zr = lane >> 2, zc = (lane & 3) * 16;
        {
            u16* zdst = zl + ((size_t)(b * T_LEN + tc + zr) * 64 + zc);
            *(short8*)zdst       = *(const short8*)&zt[wv][zr][zc];
            *(short8*)(zdst + 8) = *(const short8*)&zt[wv][zr][zc + 8];
        }

        // residual GEMM: K = 64
        f32x4 hacc[4];
        #pragma unroll
        for (int j = 0; j < 4; ++j) hacc[j] = Z;
        #pragma unroll
        for (int ks = 0; ks < 2; ++ks) {
            short8 afz = *(const short8*)&zt[wv][col][ks * 32 + quad * 8];
            #pragma unroll
            for (int j = 0; j < 4; ++j) {
                short8 wf = *(const short8*)&wshO[((ks * 64 + j * 16 + col) * 4 + quad) * 8];
                hacc[j] = MFMA16(afz, wf, hacc[j]);
            }
        }

        // res+bias -> zt (reuse; per-wave in-order LDS keeps this safe)
        #pragma unroll
        for (int j = 0; j < 4; ++j)
            #pragma unroll
            for (int r = 0; r < 4; ++r)
                zt[wv][quad * 4 + r][j * 16 + col] = bf16_rne(hacc[j][r] + bo_[j]);

        // coalesced h update: h_next = hIn + res
        const size_t hb = (size_t)(b * T_LEN + tc + zr) * 64 + zc;
        #pragma unroll
        for (int s = 0; s < 2; ++s) {
            short8 hv = *(const short8*)(hIn + hb + s * 8);
            short8 rv = *(const short8*)&zt[wv][zr][zc + s * 8];
            short8 ov;
            #pragma unroll
            for (int e = 0; e < 8; ++e)
                ov[e] = (short)bf16_rne(bf16_to_f((u16)hv[e]) + bf16_to_f((u16)rv[e]));
            *(short8*)(hOut + hb + s * 8) = ov;
        }
    }
}

// ---- skip GEMM: u = tanh(W1 @ concat_l z_l + b1) -> u bf16 (B,T,64) ----
// grid (T/64, B), 256 threads (4 waves); wave owns one 16-t chunk, K = 576.
__global__ __launch_bounds__(256, 2) void skip_kernel(
    const u16* __restrict__ zbuf, const u16* __restrict__ W1,
    const float* __restrict__ b1, u16* __restrict__ ubuf)
{
    __shared__ u16 w1sh[18 * 64 * 4 * 8];   // 72 KB [ks][o][quad][8]
    __shared__ u16 ut[4][16][64];           // 8 KB  per-wave u transpose (stride 64)

    const int b = blockIdx.y;
    const int tid = threadIdx.x;
    const int wv = tid >> 6, lane = tid & 63;
    const int quad = lane >> 4, col = lane & 15;

    #pragma unroll
    for (int rep = 0; rep < 18; ++rep) {                // 4608 x 16B
        int i = rep * 256 + tid;
        int o = i / 72, m = i % 72, ks = m >> 2, q = m & 3;
        *(short8*)&w1sh[((ks * 64 + o) * 4 + q) * 8] =
            *(const short8*)(W1 + o * 576 + ks * 32 + q * 8);
    }
    __syncthreads();

    const int tc = blockIdx.x * 64 + wv * 16;
    const int t  = tc + col;
    const f32x4 Z = {0.f, 0.f, 0.f, 0.f};

    f32x4 acc1[4] = {Z, Z, Z, Z};
    #pragma unroll
    for (int ks = 0; ks < 18; ++ks) {
        const int l = ks >> 1;
        short8 zf = *(const short8*)(zbuf + (size_t)l * ((size_t)N_B * T_LEN * 64) +
                                     ((size_t)(b * T_LEN + t) * 64 + (ks & 1) * 32 + quad * 8));
        #pragma unroll
        for (int j = 0; j < 4; ++j) {
            short8 wf = *(const short8*)&w1sh[((ks * 64 + j * 16 + col) * 4 + quad) * 8];
            acc1[j] = MFMA16(zf, wf, acc1[j]);
        }
    }

    #pragma unroll
    for (int j = 0; j < 4; ++j) {
        float bb = b1[j * 16 + col];
        #pragma unroll
        for (int r = 0; r < 4; ++r)
            ut[wv][quad * 4 + r][j * 16 + col] = bf16_rne(fast_tanh(acc1[j][r] + bb));
    }

    // coalesced u store: wave covers 16 rows x 128 B = 2 KB contiguous
    const int zr = lane >> 2, zc = (lane & 3) * 16;
    u16* ud = ubuf + ((size_t)(b * T_LEN + tc + zr) * 64 + zc);
    *(short8*)ud       = *(const short8*)&ut[wv][zr][zc];
    *(short8*)(ud + 8) = *(const short8*)&ut[wv][zr][zc + 8];
}

// ---- out GEMM: out = W2 @ u + b2, (B,256,T) fp32, full-line coalesced stores ----
// grid (T/128, B), 256 threads (4 waves); wave owns 32 t x 256 o.
__global__ __launch_bounds__(256, 2) void out_kernel(
    const u16* __restrict__ ubuf, const u16* __restrict__ W2,
    const float* __restrict__ b2, float* __restrict__ out)
{
    __shared__ u16 w2sh[2 * 256 * 4 * 8];   // 32 KB [ks][o][quad][8]
    __shared__ float otile[4][64][33];      // 33.8 KB per-wave [o][t] store tile

    const int b = blockIdx.y;
    const int tid = threadIdx.x;
    const int wv = tid >> 6, lane = tid & 63;
    const int quad = lane >> 4, col = lane & 15;

    #pragma unroll
    for (int rep = 0; rep < 8; ++rep) {                 // 2048 x 16B
        int i = rep * 256 + tid;
        int o = (i >> 2) & 255, ks = i >> 10, q = i & 3;
        *(short8*)&w2sh[((ks * 256 + o) * 4 + q) * 8] =
            *(const short8*)(W2 + o * 64 + ks * 32 + q * 8);
    }
    __syncthreads();

    const int t0 = blockIdx.x * 128 + wv * 32;

    // B-frags: u for the wave's two 16-t chunks (u read exactly once per element)
    short8 bf[2][2];
    #pragma unroll
    for (int c = 0; c < 2; ++c)
        #pragma unroll
        for (int ks = 0; ks < 2; ++ks)
            bf[c][ks] = *(const short8*)(ubuf +
                ((size_t)(b * T_LEN + t0 + c * 16 + col) * 64 + ks * 32 + quad * 8));

    const f32x4 Z = {0.f, 0.f, 0.f, 0.f};
    f32x4 acc[2][16];
    #pragma unroll
    for (int c = 0; c < 2; ++c)
        #pragma unroll
        for (int mm = 0; mm < 16; ++mm) acc[c][mm] = Z;

    // A = W2 (m = o), B = u (n = t): D(o = mm*16+quad*4+r, t = tc+col)
    #pragma unroll
    for (int mm = 0; mm < 16; ++mm) {
        short8 a0 = *(const short8*)&w2sh[((mm * 16 + col) * 4 + quad) * 8];
        short8 a1 = *(const short8*)&w2sh[((256 + mm * 16 + col) * 4 + quad) * 8];
        #pragma unroll
        for (int c = 0; c < 2; ++c) {
            acc[c][mm] = MFMA16(a0, bf[c][0], acc[c][mm]);
            acc[c][mm] = MFMA16(a1, bf[c][1], acc[c][mm]);
        }
    }

    // epilogue: 4 o-slices of 64; route through LDS -> 1-KB full-line wave stores
    const int orow = lane >> 3, tof = (lane & 7) * 4;
    #pragma unroll
    for (int s = 0; s < 4; ++s) {
        #pragma unroll
        for (int m4 = 0; m4 < 4; ++m4) {
            const int mm = s * 4 + m4;
            f32x4 bq = *(const f32x4*)(b2 + mm * 16 + quad * 4);
            #pragma unroll
            for (int c = 0; c < 2; ++c)
                #pragma unroll
                for (int r = 0; r < 4; ++r)
                    otile[wv][m4 * 16 + quad * 4 + r][c * 16 + col] = acc[c][mm][r] + bq[r];
        }
        // per-wave in-order LDS: writes above complete before reads below
        #pragma unroll
        for (int i8 = 0; i8 < 8; ++i8) {
            const int ol = i8 * 8 + orow;
            f32x4 vv = {otile[wv][ol][tof],     otile[wv][ol][tof + 1],
                        otile[wv][ol][tof + 2], otile[wv][ol][tof + 3]};
            *(f32x4*)(out + (size_t)(b * 256 + s * 64 + ol) * T_LEN + t0 + tof) = vv;
        }
    }
}

extern "C" void kernel_launch(void* const* d_in, const int* in_sizes, int n_in,
                              void* d_out, int out_size, void* d_ws, size_t ws_size,
                              hipStream_t stream)
{
    const float* x  = (const float*)d_in[0];
    const float* wi = (const float*)d_in[1];
    const float* bi = (const float*)d_in[2];
    const float* wc = (const float*)d_in[3];
    const float* bc = (const float*)d_in[4];
    const float* wo = (const float*)d_in[5];
    const float* bo = (const float*)d_in[6];
    const float* w1 = (const float*)d_in[7];
    const float* b1 = (const float*)d_in[8];
    const float* w2 = (const float*)d_in[9];
    const float* b2 = (const float*)d_in[10];
    float* out = (float*)d_out;

    char* ws = (char*)d_ws;
    const size_t HBYTES = (size_t)N_B * T_LEN * 64 * 2;   // 16 MB
    u16* hA   = (u16*)ws;
    u16* hB   = (u16*)(ws + HBYTES);
    u16* zAll = (u16*)(ws + 2 * HBYTES);                  // 9 x 16 MB
    u16* uBuf = (u16*)(ws + 11 * HBYTES);
    size_t off = 12 * HBYTES;
    u16* Wc  = (u16*)(ws + off); off += (size_t)9 * 128 * 192 * 2;
    u16* Wo  = (u16*)(ws + off); off += (size_t)9 * 64 * 64 * 2;
    u16* W1p = (u16*)(ws + off); off += (size_t)64 * 576 * 2;
    u16* W2p = (u16*)(ws + off); off += (size_t)256 * 64 * 2;
    if (ws_size < off) return;   // needs ~193 MB of workspace

    pack_kernel<<<1216, 256, 0, stream>>>(wc, wo, w1, w2, Wc, Wo, W1p, W2p);
    input_kernel<<<(N_B * T_LEN) / 256, 256, 0, stream>>>(x, wi, bi, hA);

    static const int dil[9] = {1, 2, 4, 8, 16, 32, 64, 128, 256};
    for (int l = 0; l < 9; ++l) {
        const u16* hin = (l & 1) ? hB : hA;
        u16* hout      = (l & 1) ? hA : hB;
        layer_kernel<<<dim3(T_LEN / 256, N_B), 512, 0, stream>>>(
            hin, hout, zAll, Wc, Wo, bc, bo, l, dil[l]);
    }
    skip_kernel<<<dim3(T_LEN / 64, N_B), 256, 0, stream>>>(zAll, W1p, b1, uBuf);
    out_kernel<<<dim3(T_LEN / 128, N_B), 256, 0, stream>>>(uBuf, W2p, b2, out);
}